// Round 2
// baseline (237.542 us; speedup 1.0000x reference)
//
#include <hip/hip_runtime.h>

// out[b,s] = cumsum_s( softplus(beta * c[b,s]) / beta ), fp32, B=4096, S=8192.
//
// R3b design (R3 + nt-store type fix): persistent pipelined blocks.
//   - 1024 blocks x 512 threads (8 waves) -> 4 blocks/CU resident for the
//     whole kernel (VGPR <= 64 via __launch_bounds__(512,8)); one launch
//     round, no convoy refills.
//   - Each block owns 4 rows. Next row's 4 coalesced float4 loads are issued
//     right after the current row's softplus consumes v[], so they fly during
//     the shuffle-scan + barrier + combine + store phase. Steady state:
//     memory ops always outstanding (R2: burst-load -> silent compute ->
//     burst-store, HBM duty ~30%).
//   - NJ = 4 (was 8): per-thread wave-scan work halves (24 shuffle steps).
//   - wave_sums double-buffered on row parity -> ONE barrier per row.
//   - Nontemporal stores via native ext_vector_type (HIP float4 class type is
//     rejected by __builtin_nontemporal_store): out is never re-read; avoid
//     evicting the input from L3 (FETCH was already only half the input).

#define ROW_S   8192
#define BLOCK_T 512
#define NJ      (ROW_S / 4 / BLOCK_T)   // 4 float4 chunks per thread per row
#define NWAVE   (BLOCK_T / 64)          // 8 waves per block
#define ROWS    4                       // rows per block (software pipeline)

typedef float f32x4 __attribute__((ext_vector_type(4)));

__device__ __forceinline__ float softplus_step(float c, float beta, float inv_beta) {
    float tb = beta * c;
    float a  = fabsf(tb);
    float e  = __expf(-a);             // in (0,1], no overflow
    float l  = __logf(1.0f + e);       // log1p(exp(-|t|))
    return (fmaxf(tb, 0.0f) + l) * inv_beta;
}

__global__ __launch_bounds__(BLOCK_T, 8) void softplus_cumsum_kernel(
    const float* __restrict__ c,
    const float* __restrict__ beta_p,
    float* __restrict__ out,
    int nrows, int grid)
{
    __shared__ float wave_sums[2][NJ][NWAVE];   // 256 B, parity double-buffered

    const int t    = threadIdx.x;
    const int lane = t & 63;
    const int wave = t >> 6;

    const float beta     = beta_p[0];
    const float inv_beta = 1.0f / beta;

    const int    row0 = blockIdx.x;
    const size_t rs4  = (size_t)grid * (ROW_S / 4);     // row stride in f32x4

    const f32x4* __restrict__ in4  = (const f32x4*)c   + (size_t)row0 * (ROW_S / 4);
    f32x4*       __restrict__ out4 = (f32x4*)out       + (size_t)row0 * (ROW_S / 4);

    // ---- prologue: loads for this block's first row ----
    f32x4 v[NJ];
    #pragma unroll
    for (int j = 0; j < NJ; ++j)
        v[j] = in4[j * BLOCK_T + t];

    #pragma unroll
    for (int i = 0; i < ROWS; ++i) {
        const int cur_row = row0 + i * grid;
        if (cur_row >= nrows) break;                    // block-uniform

        // ---- softplus + in-chunk inclusive scan (consumes v[]) ----
        f32x4 r[NJ];
        #pragma unroll
        for (int j = 0; j < NJ; ++j) {
            float a = softplus_step(v[j].x, beta, inv_beta);
            float b = softplus_step(v[j].y, beta, inv_beta);
            float d = softplus_step(v[j].z, beta, inv_beta);
            float e = softplus_step(v[j].w, beta, inv_beta);
            r[j].x = a;
            r[j].y = a + b;
            r[j].z = r[j].y + d;
            r[j].w = r[j].z + e;
        }

        // ---- prefetch next row NOW: flies under scan+barrier+store ----
        if (i + 1 < ROWS && cur_row + grid < nrows) {
            #pragma unroll
            for (int j = 0; j < NJ; ++j)
                v[j] = in4[rs4 + j * BLOCK_T + t];
        }

        // ---- wave-inclusive shuffle scans of the NJ chunk sums ----
        float xscan[NJ];
        #pragma unroll
        for (int j = 0; j < NJ; ++j) {
            float x = r[j].w;
            #pragma unroll
            for (int d = 1; d < 64; d <<= 1) {
                float y = __shfl_up(x, d, 64);
                if (lane >= d) x += y;
            }
            xscan[j] = x;
            if (lane == 63) wave_sums[i & 1][j][wave] = x;
        }
        __syncthreads();                                // the ONE barrier/row

        // ---- combine: group carry + wave-exclusive + lane-exclusive ----
        float carry = 0.0f;
        #pragma unroll
        for (int j = 0; j < NJ; ++j) {
            float woff = 0.0f, btot = 0.0f;
            #pragma unroll
            for (int w = 0; w < NWAVE; ++w) {
                float ws = wave_sums[i & 1][j][w];      // broadcast read
                if (w < wave) woff += ws;               // wave-uniform predicate
                btot += ws;
            }
            const float off = carry + woff + (xscan[j] - r[j].w);
            carry += btot;

            f32x4 o;
            o.x = r[j].x + off;
            o.y = r[j].y + off;
            o.z = r[j].z + off;
            o.w = r[j].w + off;
            __builtin_nontemporal_store(o, &out4[j * BLOCK_T + t]);  // nt store
        }

        in4  += rs4;
        out4 += rs4;
    }
}

extern "C" void kernel_launch(void* const* d_in, const int* in_sizes, int n_in,
                              void* d_out, int out_size, void* d_ws, size_t ws_size,
                              hipStream_t stream) {
    const float* c      = (const float*)d_in[0];
    const float* beta_p = (const float*)d_in[1];
    float*       out    = (float*)d_out;

    const int B    = in_sizes[0] / ROW_S;               // 4096 rows
    const int grid = (B + ROWS - 1) / ROWS;             // 1024 blocks

    softplus_cumsum_kernel<<<dim3(grid), dim3(BLOCK_T), 0, stream>>>(
        c, beta_p, out, B, grid);
}